// Round 3
// baseline (472.845 us; speedup 1.0000x reference)
//
#include <hip/hip_runtime.h>

#define I_DIM 1025
#define J_DIM 2048
#define K_B 8
#define IC 33            // i-chunks of 32 (last chunk has 1)
#define EPSF 1e-20f

// ---------------- helpers ----------------

template<int NV>
__device__ __forceinline__ void shflReduce(float* v) {
  #pragma unroll
  for (int off = 32; off > 0; off >>= 1) {
    #pragma unroll
    for (int q = 0; q < NV; ++q) v[q] += __shfl_down(v[q], off);
  }
}

__device__ __forceinline__ float2 cmul(float2 a, float2 b) {
  return make_float2(a.x*b.x - a.y*b.y, a.x*b.y + a.y*b.x);
}
__device__ __forceinline__ float2 cadd(float2 a, float2 b) {
  return make_float2(a.x + b.x, a.y + b.y);
}
__device__ __forceinline__ float2 csub(float2 a, float2 b) {
  return make_float2(a.x - b.x, a.y - b.y);
}
__device__ __forceinline__ float2 cdiv(float2 a, float2 b) {
  float s = 1.0f / (b.x*b.x + b.y*b.y);
  return make_float2((a.x*b.x + a.y*b.y)*s, (a.y*b.x - a.x*b.y)*s);
}

// ---------------- init ----------------
// T layout: [n][i][k]   (2 x 1025 x 8)
// V layout: [k][j][n]   float2-packed == V0 native layout (verbatim copy)
// W layout: [i][n][m][c] (1025 x 8 floats), complex interleaved
__global__ __launch_bounds__(256) void k_init(
    const float* __restrict__ T0, const float* __restrict__ V0,
    float* __restrict__ T, float* __restrict__ V, float* __restrict__ W)
{
  int t = blockIdx.x * 256 + threadIdx.x;
  if (t < 2 * K_B * J_DIM) V[t] = V0[t];   // verbatim copy (layout matches)
  if (t < 2 * I_DIM * K_B) {               // T: 16400
    int n = t / (I_DIM * K_B);
    int r = t % (I_DIM * K_B);
    int i = r / K_B, k = r % K_B;
    T[t] = T0[(i * K_B + k) * 2 + n];
  }
  if (t < I_DIM * 8) {                     // W: 8200
    int u = t & 7;
    int c = u & 1, m = (u >> 1) & 1, n = u >> 2;
    W[t] = (n == m && c == 0) ? 1.0f : 0.0f;
  }
}

// ---------------- transpose X (M,J,I,2) -> Xq[i][j] = (re0,im0,re1,im1) -----
__global__ __launch_bounds__(256) void k_transpose(
    const float* __restrict__ X, float4* __restrict__ Xq)
{
  __shared__ float t0r[32][33], t0i[32][33], t1r[32][33], t1i[32][33];
  const int i0 = blockIdx.x * 32, j0 = blockIdx.y * 32;
  const int tx = threadIdx.x, ty = threadIdx.y;  // (32, 8)
  const float2* __restrict__ X2 = (const float2*)X;
  #pragma unroll
  for (int jj = 0; jj < 4; ++jj) {
    int jl = ty + jj * 8;
    int i = i0 + tx;
    if (i < I_DIM) {
      float2 v0 = X2[(size_t)(0 * J_DIM + j0 + jl) * I_DIM + i];
      float2 v1 = X2[(size_t)(1 * J_DIM + j0 + jl) * I_DIM + i];
      t0r[jl][tx] = v0.x; t0i[jl][tx] = v0.y;
      t1r[jl][tx] = v1.x; t1i[jl][tx] = v1.y;
    }
  }
  __syncthreads();
  #pragma unroll
  for (int ii = 0; ii < 4; ++ii) {
    int il = ty + ii * 8;
    int i = i0 + il;
    if (i < I_DIM) {
      Xq[(size_t)i * J_DIM + j0 + tx] =
        make_float4(t0r[tx][il], t0i[tx][il], t1r[tx][il], t1i[tx][il]);
    }
  }
}

// ---------------- NMF T-step body -------------------------------------------
template<int N>
__device__ __forceinline__ void nmfT_body(
    int i, int tid,
    const float4* __restrict__ Xq,
    float* __restrict__ T, const float2* __restrict__ V2,
    const float* __restrict__ W, float* __restrict__ YdR)
{
  const float4 w = ((const float4*)W)[i * 2 + N];
  float t[K_B];
  const int trow = (N * I_DIM + i) * K_B;
  #pragma unroll
  for (int k = 0; k < K_B; ++k) t[k] = T[trow + k];

  float num[K_B], den[K_B];
  #pragma unroll
  for (int k = 0; k < K_B; ++k) { num[k] = 0.f; den[k] = 0.f; }

  #pragma unroll
  for (int jj = 0; jj < J_DIM / 256; ++jj) {
    int j = jj * 256 + tid;
    float4 x = Xq[(size_t)i * J_DIM + j];
    float yr = w.x * x.x - w.y * x.y + w.z * x.z - w.w * x.w;
    float yi = w.x * x.y + w.y * x.x + w.z * x.w + w.w * x.z;
    float ym2 = yr * yr + yi * yi;
    float v[K_B];
    float rn = 0.f;
    #pragma unroll
    for (int k = 0; k < K_B; ++k) {
      float2 v2 = V2[k * J_DIM + j];
      v[k] = (N == 0) ? v2.x : v2.y;
      rn += t[k] * v[k];
    }
    float mr = fabsf(rn);
    float ydr = ym2 / (mr * mr + EPSF);
    float rd = 1.0f / (mr + EPSF);
    YdR[(size_t)i * J_DIM + j] = ydr;
    #pragma unroll
    for (int k = 0; k < K_B; ++k) { num[k] += ydr * v[k]; den[k] += rd * v[k]; }
  }

  float vals[16];
  #pragma unroll
  for (int k = 0; k < K_B; ++k) { vals[k] = num[k]; vals[K_B + k] = den[k]; }
  shflReduce<16>(vals);
  __shared__ float redT[4][16];
  int wave = tid >> 6, lane = tid & 63;
  if (lane == 0) {
    #pragma unroll
    for (int q = 0; q < 16; ++q) redT[wave][q] = vals[q];
  }
  __syncthreads();
  if (tid < K_B) {
    float nm = redT[0][tid] + redT[1][tid] + redT[2][tid] + redT[3][tid];
    float dn = redT[0][tid + 8] + redT[1][tid + 8] + redT[2][tid + 8] + redT[3][tid + 8];
    T[trow + tid] *= sqrtf(nm / (dn + EPSF));
  }
}

// ---------------- 2x2 solve epilogue (one thread) ----------------------------
template<int N>
__device__ __forceinline__ void ip_solve(
    int i, float D00, float p, float q, float D11, float* __restrict__ W)
{
  D00 += EPSF; D11 += EPSF;
  float2 D01 = make_float2(p, q);
  float2 D10 = make_float2(p, -q);
  float4 w0 = ((const float4*)W)[i * 2 + 0];
  float4 w1 = ((const float4*)W)[i * 2 + 1];
  float2 W00 = make_float2(w0.x, w0.y), W01 = make_float2(w0.z, w0.w);
  float2 W10 = make_float2(w1.x, w1.y), W11 = make_float2(w1.z, w1.w);
  float2 A00 = cadd(make_float2(W00.x * D00, W00.y * D00), cmul(W01, D10));
  float2 A01 = cadd(cmul(W00, D01), make_float2(W01.x * D11, W01.y * D11));
  float2 A10 = cadd(make_float2(W10.x * D00, W10.y * D00), cmul(W11, D10));
  float2 A11 = cadd(cmul(W10, D01), make_float2(W11.x * D11, W11.y * D11));
  float2 det = csub(cmul(A00, A11), cmul(A01, A10));
  float2 b0, b1;
  if (N == 0) {
    b0 = cdiv(A11, det);
    b1 = cdiv(make_float2(-A10.x, -A10.y), det);
  } else {
    b0 = cdiv(make_float2(-A01.x, -A01.y), det);
    b1 = cdiv(A00, det);
  }
  float2 Db0 = cadd(make_float2(D00 * b0.x, D00 * b0.y), cmul(D01, b1));
  float2 Db1 = cadd(cmul(D10, b0), make_float2(D11 * b1.x, D11 * b1.y));
  float ip = b0.x * Db0.x + b0.y * Db0.y + b1.x * Db1.x + b1.y * Db1.y;
  float inv = 1.0f / sqrtf(ip + EPSF);
  ((float4*)W)[i * 2 + N] = make_float4(b0.x * inv, -b0.y * inv, b1.x * inv, -b1.y * inv);
}

// ---------------- IP standalone body -----------------------------------------
template<int N>
__device__ __forceinline__ void ip_body(
    int i, int tid,
    const float4* __restrict__ Xq,
    const float* __restrict__ T, const float2* __restrict__ V2,
    float* __restrict__ W)
{
  float t[K_B];
  const int trow = (N * I_DIM + i) * K_B;
  #pragma unroll
  for (int k = 0; k < K_B; ++k) t[k] = T[trow + k];

  float d00 = 0.f, d01r = 0.f, d01i = 0.f, d11 = 0.f;
  #pragma unroll
  for (int jj = 0; jj < J_DIM / 256; ++jj) {
    int j = jj * 256 + tid;
    float4 x = Xq[(size_t)i * J_DIM + j];
    float rn = 0.f;
    #pragma unroll
    for (int k = 0; k < K_B; ++k) {
      float2 v2 = V2[k * J_DIM + j];
      rn += t[k] * ((N == 0) ? v2.x : v2.y);
    }
    float wgt = 1.0f / (rn + EPSF);
    d00 += (x.x * x.x + x.y * x.y) * wgt;
    d11 += (x.z * x.z + x.w * x.w) * wgt;
    d01r += (x.x * x.z + x.y * x.w) * wgt;
    d01i += (x.y * x.z - x.x * x.w) * wgt;
  }
  float vals[4] = {d00, d01r, d01i, d11};
  shflReduce<4>(vals);
  __shared__ float redI[4][4];
  int wave = tid >> 6, lane = tid & 63;
  if (lane == 0) {
    #pragma unroll
    for (int q = 0; q < 4; ++q) redI[wave][q] = vals[q];
  }
  __syncthreads();
  if (tid == 0) {
    const float invJ = 1.0f / (float)J_DIM;
    ip_solve<N>(i,
      (redI[0][0] + redI[1][0] + redI[2][0] + redI[3][0]) * invJ,
      (redI[0][1] + redI[1][1] + redI[2][1] + redI[3][1]) * invJ,
      (redI[0][2] + redI[1][2] + redI[2][2] + redI[3][2]) * invJ,
      (redI[0][3] + redI[1][3] + redI[2][3] + redI[3][3]) * invJ, W);
  }
}

// ---------------- combined single-pass: ip(N_IP) + nmfT(N_T), one block per i
template<int N_IP, int N_T>
__global__ __launch_bounds__(256) void k_comb(
    const float4* __restrict__ Xq, float* __restrict__ T,
    const float2* __restrict__ V2, float* __restrict__ W,
    float* __restrict__ YdR)
{
  const int i = blockIdx.x;
  const int tid = threadIdx.x;
  const float4 w = ((const float4*)W)[i * 2 + N_T];   // read BEFORE W[N_IP] write
  float t_ip[K_B], t_t[K_B];
  const int trow_ip = (N_IP * I_DIM + i) * K_B;
  const int trow_t  = (N_T  * I_DIM + i) * K_B;
  #pragma unroll
  for (int k = 0; k < K_B; ++k) { t_ip[k] = T[trow_ip + k]; t_t[k] = T[trow_t + k]; }

  float num[K_B], den[K_B];
  #pragma unroll
  for (int k = 0; k < K_B; ++k) { num[k] = 0.f; den[k] = 0.f; }
  float d00 = 0.f, d01r = 0.f, d01i = 0.f, d11 = 0.f;

  #pragma unroll
  for (int jj = 0; jj < J_DIM / 256; ++jj) {
    int j = jj * 256 + tid;
    float4 x = Xq[(size_t)i * J_DIM + j];
    float vt[K_B];
    float rn_ip = 0.f, rn_t = 0.f;
    #pragma unroll
    for (int k = 0; k < K_B; ++k) {
      float2 v2 = V2[k * J_DIM + j];
      float vip = (N_IP == 0) ? v2.x : v2.y;
      float vt_ = (N_T  == 0) ? v2.x : v2.y;
      rn_ip += t_ip[k] * vip;
      rn_t  += t_t[k] * vt_;
      vt[k] = vt_;
    }
    // --- ip accumulation (source N_IP) ---
    float wgt = 1.0f / (rn_ip + EPSF);
    d00 += (x.x * x.x + x.y * x.y) * wgt;
    d11 += (x.z * x.z + x.w * x.w) * wgt;
    d01r += (x.x * x.z + x.y * x.w) * wgt;
    d01i += (x.y * x.z - x.x * x.w) * wgt;
    // --- nmfT accumulation (source N_T) ---
    float yr = w.x * x.x - w.y * x.y + w.z * x.z - w.w * x.w;
    float yi = w.x * x.y + w.y * x.x + w.z * x.w + w.w * x.z;
    float ym2 = yr * yr + yi * yi;
    float mr = fabsf(rn_t);
    float ydr = ym2 / (mr * mr + EPSF);
    float rd = 1.0f / (mr + EPSF);
    YdR[(size_t)i * J_DIM + j] = ydr;
    #pragma unroll
    for (int k = 0; k < K_B; ++k) { num[k] += ydr * vt[k]; den[k] += rd * vt[k]; }
  }

  float vals[20];
  #pragma unroll
  for (int k = 0; k < K_B; ++k) { vals[k] = num[k]; vals[K_B + k] = den[k]; }
  vals[16] = d00; vals[17] = d01r; vals[18] = d01i; vals[19] = d11;
  shflReduce<20>(vals);
  __shared__ float red[4][20];
  int wave = tid >> 6, lane = tid & 63;
  if (lane == 0) {
    #pragma unroll
    for (int q = 0; q < 20; ++q) red[wave][q] = vals[q];
  }
  __syncthreads();
  if (tid < K_B) {
    float nm = red[0][tid] + red[1][tid] + red[2][tid] + red[3][tid];
    float dn = red[0][tid + 8] + red[1][tid + 8] + red[2][tid + 8] + red[3][tid + 8];
    T[trow_t + tid] *= sqrtf(nm / (dn + EPSF));
  }
  if (tid == 0) {
    const float invJ = 1.0f / (float)J_DIM;
    ip_solve<N_IP>(i,
      (red[0][16] + red[1][16] + red[2][16] + red[3][16]) * invJ,
      (red[0][17] + red[1][17] + red[2][17] + red[3][17]) * invJ,
      (red[0][18] + red[1][18] + red[2][18] + red[3][18]) * invJ,
      (red[0][19] + red[1][19] + red[2][19] + red[3][19]) * invJ, W);
  }
}

// ---------------- standalone wrappers ----------------
template<int N>
__global__ __launch_bounds__(256) void k_nmfT(
    const float4* __restrict__ Xq, float* __restrict__ T,
    const float2* __restrict__ V2, const float* __restrict__ W,
    float* __restrict__ YdR)
{
  nmfT_body<N>(blockIdx.x, threadIdx.x, Xq, T, V2, W, YdR);
}

template<int N>
__global__ __launch_bounds__(256) void k_ip(
    const float4* __restrict__ Xq, const float* __restrict__ T,
    const float2* __restrict__ V2, float* __restrict__ W)
{
  ip_body<N>(blockIdx.x, threadIdx.x, Xq, T, V2, W);
}

// ---------------- NMF V-step, phase A: partial sums --------------------------
template<int N>
__global__ __launch_bounds__(256) void k_nmfVpart(
    const float* __restrict__ T, const float2* __restrict__ V2,
    const float* __restrict__ YdR,
    float* __restrict__ Pn, float* __restrict__ Pd)
{
  const int tid = threadIdx.x;
  const int jb = blockIdx.x & 7;
  const int c  = blockIdx.x >> 3;
  const int j  = jb * 256 + tid;
  const int i0 = c * 32;
  const int ni = min(32, I_DIM - i0);
  __shared__ float sT[32][K_B];
  if (tid < ni * K_B) sT[tid >> 3][tid & 7] = T[(N * I_DIM + i0) * K_B + tid];
  __syncthreads();
  float v[K_B];
  #pragma unroll
  for (int k = 0; k < K_B; ++k) {
    float2 v2 = V2[k * J_DIM + j];
    v[k] = (N == 0) ? v2.x : v2.y;
  }
  float num[K_B], den[K_B];
  #pragma unroll
  for (int k = 0; k < K_B; ++k) { num[k] = 0.f; den[k] = 0.f; }
  for (int ii = 0; ii < ni; ++ii) {
    float ydr = YdR[(size_t)(i0 + ii) * J_DIM + j];
    float rn = 0.f;
    #pragma unroll
    for (int k = 0; k < K_B; ++k) rn += sT[ii][k] * v[k];
    float rd2 = 1.0f / (fabsf(rn) + EPSF);
    #pragma unroll
    for (int k = 0; k < K_B; ++k) { num[k] += sT[ii][k] * ydr; den[k] += sT[ii][k] * rd2; }
  }
  #pragma unroll
  for (int k = 0; k < K_B; ++k) {
    Pn[((size_t)c * K_B + k) * J_DIM + j] = num[k];
    Pd[((size_t)c * K_B + k) * J_DIM + j] = den[k];
  }
}

// ---------------- NMF V-step, phase B: finalize ------------------------------
template<int N>
__global__ __launch_bounds__(256) void k_nmfVfin(
    float* __restrict__ V, const float* __restrict__ Pn,
    const float* __restrict__ Pd)
{
  const int t = blockIdx.x * 256 + threadIdx.x;   // k*2048+j, 16384 total
  float nm = 0.f, dn = 0.f;
  #pragma unroll 11
  for (int c = 0; c < IC; ++c) {
    nm += Pn[(size_t)c * (K_B * J_DIM) + t];
    dn += Pd[(size_t)c * (K_B * J_DIM) + t];
  }
  V[2 * t + N] *= sqrtf(nm / (dn + EPSF));
}

// ---------------- output: Y = W @ Xc, layout (N, J, I, 2) --------------------
__global__ __launch_bounds__(256) void k_out(
    const float* __restrict__ X, const float* __restrict__ W, float* __restrict__ out)
{
  const int j = blockIdx.x;
  const int i = blockIdx.y * 256 + threadIdx.x;
  if (i >= I_DIM) return;
  const float2* __restrict__ X2 = (const float2*)X;
  float2 x0 = X2[(size_t)(0 * J_DIM + j) * I_DIM + i];
  float2 x1 = X2[(size_t)(1 * J_DIM + j) * I_DIM + i];
  const float4* __restrict__ W4 = (const float4*)W;
  float4 w0 = W4[i * 2 + 0];
  float4 w1 = W4[i * 2 + 1];
  float2* __restrict__ O = (float2*)out;
  float yr = w0.x * x0.x - w0.y * x0.y + w0.z * x1.x - w0.w * x1.y;
  float yi = w0.x * x0.y + w0.y * x0.x + w0.z * x1.y + w0.w * x1.x;
  O[(size_t)(0 * J_DIM + j) * I_DIM + i] = make_float2(yr, yi);
  yr = w1.x * x0.x - w1.y * x0.y + w1.z * x1.x - w1.w * x1.y;
  yi = w1.x * x0.y + w1.y * x0.x + w1.z * x1.y + w1.w * x1.x;
  O[(size_t)(1 * J_DIM + j) * I_DIM + i] = make_float2(yr, yi);
}

// ---------------- launch ----------------
extern "C" void kernel_launch(void* const* d_in, const int* in_sizes, int n_in,
                              void* d_out, int out_size, void* d_ws, size_t ws_size,
                              hipStream_t stream) {
  const float* X  = (const float*)d_in[0];   // (2, 2048, 1025, 2)
  const float* T0 = (const float*)d_in[1];   // (1025, 8, 2)
  const float* V0 = (const float*)d_in[2];   // (8, 2048, 2)
  float* ws = (float*)d_ws;
  // workspace layout (floats)
  float4* Xq = (float4*)ws;           // 1025*2048 float4 = 8396800 floats
  float* YdR = ws + 8396800;          // 2099200
  float* T   = ws + 10496000;         // 16400
  float* V   = ws + 10512400;         // 32768 (float2-packed [k][j][n])
  float* W   = ws + 10545168;         // 8200
  float* Pn  = ws + 10553368;         // 540672
  float* Pd  = ws + 11094040;         // 540672
  float2* V2 = (float2*)V;
  float* out = (float*)d_out;

  k_init<<<128, 256, 0, stream>>>(T0, V0, T, V, W);
  k_transpose<<<dim3(33, 64), dim3(32, 8), 0, stream>>>(X, Xq);
  k_nmfT<0><<<I_DIM, 256, 0, stream>>>(Xq, T, V2, W, YdR);
  for (int it = 0; it < 5; ++it) {
    k_nmfVpart<0><<<8 * IC, 256, 0, stream>>>(T, V2, YdR, Pn, Pd);
    k_nmfVfin<0><<<64, 256, 0, stream>>>(V, Pn, Pd);
    k_comb<0, 1><<<I_DIM, 256, 0, stream>>>(Xq, T, V2, W, YdR);
    k_nmfVpart<1><<<8 * IC, 256, 0, stream>>>(T, V2, YdR, Pn, Pd);
    k_nmfVfin<1><<<64, 256, 0, stream>>>(V, Pn, Pd);
    if (it < 4) {
      k_comb<1, 0><<<I_DIM, 256, 0, stream>>>(Xq, T, V2, W, YdR);
    } else {
      k_ip<1><<<I_DIM, 256, 0, stream>>>(Xq, T, V2, W);
    }
  }
  k_out<<<dim3(J_DIM, 5), 256, 0, stream>>>(X, W, out);
}